// Round 4
// baseline (195.170 us; speedup 1.0000x reference)
//
#include <hip/hip_runtime.h>
#include <math.h>

// Problem constants
#define N_ROWS 100000
#define IN_C   256
#define OUT_C  128
#define NHEAD  4
#define NCLS   1000
#define NCOPY  16      // privatization factor for histogram/buckets
#define CAP    64      // bucket capacity per (copy,class); lambda=6.25, ~10-sigma margin

// Workspace layout (float/uint elements); ~1.04M elems = 4.2 MB
#define OFF_V      0          // 1024: folded V[4][256]
#define OFF_CB     1024       // 4:    folded bias c[4]
#define OFF_CNT    1032       // NCOPY*NCLS = 16000 privatized counters
#define OFF_BUCKET 17032      // NCOPY*NCLS*CAP = 1,024,000 row-id buckets

// ---- K1: fused counter zero + weight folding ----
__global__ __launch_bounds__(256) void k_prep(const float* __restrict__ W_lin,
                                              const float* __restrict__ b_lin,
                                              const float* __restrict__ W_att,
                                              const float* __restrict__ b_att,
                                              float* __restrict__ ws) {
    const int b = blockIdx.x, t = threadIdx.x;
    if (b >= NHEAD) {
        int i = (b - NHEAD) * 256 + t;   // 63*256 = 16128 >= 16000
        if (i < NCOPY * NCLS) ((unsigned*)(ws + OFF_CNT))[i] = 0u;
        return;
    }
    __shared__ float sw[OUT_C];
    __shared__ float rb[256];
    if (t < OUT_C) sw[t] = W_att[t];
    __syncthreads();
    const float* wl = W_lin + (size_t)(b * OUT_C) * IN_C + t;
    float s0 = 0.f, s1 = 0.f, s2 = 0.f, s3 = 0.f;
    #pragma unroll 8
    for (int o = 0; o < OUT_C; o += 4) {
        s0 = fmaf(wl[(size_t)(o + 0) * IN_C], sw[o + 0], s0);
        s1 = fmaf(wl[(size_t)(o + 1) * IN_C], sw[o + 1], s1);
        s2 = fmaf(wl[(size_t)(o + 2) * IN_C], sw[o + 2], s2);
        s3 = fmaf(wl[(size_t)(o + 3) * IN_C], sw[o + 3], s3);
    }
    (ws + OFF_V)[b * IN_C + t] = (s0 + s1) + (s2 + s3);
    rb[t] = (t < OUT_C) ? b_lin[b * OUT_C + t] * sw[t] : 0.f;
    __syncthreads();
    for (int d = 128; d; d >>= 1) {
        if (t < d) rb[t] += rb[t + d];
        __syncthreads();
    }
    if (t == 0) (ws + OFF_CB)[b] = rb[0] + b_att[0];
}

// ---- K2: bucket rows by class (reads ONLY y — no ch traffic) ----
__global__ __launch_bounds__(256) void k_bucket(const int* __restrict__ y,
                                                float* __restrict__ ws) {
    int n0 = (blockIdx.x * 256 + threadIdx.x) * 2;
    if (n0 >= N_ROWS) return;
    unsigned* cnt    = (unsigned*)(ws + OFF_CNT);
    unsigned* bucket = (unsigned*)(ws + OFF_BUCKET);
    int2 yv = *(const int2*)(y + n0);          // N_ROWS even; n0+1 always valid
    unsigned cp = (blockIdx.x & (NCOPY - 1)) * NCLS;
    unsigned i0 = cp + (unsigned)yv.x;
    unsigned p0 = atomicAdd(&cnt[i0], 1u);     // ~6.25 adds/address avg
    if (p0 < CAP) bucket[i0 * CAP + p0] = (unsigned)n0;
    unsigned i1 = cp + (unsigned)yv.y;
    unsigned p1 = atomicAdd(&cnt[i1], 1u);
    if (p1 < CAP) bucket[i1 * CAP + p1] = (unsigned)(n0 + 1);
}

// ---- K3: single-pass pooling ----
// v2b: 8 rows per wave-iteration (stride 64), double-buffered one iteration
// ahead. The 4-level __shfl_xor butterflies are emitted LEVEL-BY-LEVEL across
// the 8 rows so their DS-op chains pipeline with ILP=8 instead of serializing
// per row (Round-2 counters: 60us with HBM 12%, VALU 26%, conflicts 0 =
// latency-bound smear from per-row serial chains + 6KB/wave in flight).
// NOTE macro params are X_/E_/P_/J_ — a param named `x` also substitutes the
// `.x` member tokens (Round-3 compile failure).
__global__ __launch_bounds__(512) void k_pool(const float* __restrict__ ch,
                                              float* __restrict__ out,
                                              const float* __restrict__ ws) {
    __shared__ unsigned rowbuf[NCOPY * CAP + 8];  // +8 pad: uint4 reads stay in-bounds
    __shared__ float4   sAcc[NHEAD][4][64];       // paired-wave partials (16 KB)
    __shared__ float4   sDs[8];                   // per-wave denom partials
    const int c = blockIdx.x, t = threadIdx.x;
    const int wave = t >> 6, lane = t & 63;
    const unsigned* cntA   = (const unsigned*)(ws + OFF_CNT);
    const unsigned* bucket = (const unsigned*)(ws + OFF_BUCKET);
    float* o = out + (size_t)c * (NHEAD * IN_C);

    // Per-copy counts (uniform) + exclusive prefix + total
    unsigned cc[NCOPY], pre[NCOPY];
    unsigned cnt = 0;
    #pragma unroll
    for (int cp = 0; cp < NCOPY; ++cp) {
        unsigned v = cntA[cp * NCLS + c];
        cc[cp] = v > CAP ? CAP : v;
        pre[cp] = cnt;
        cnt += cc[cp];
    }
    if (cnt == 0) {  // empty segment -> zeros
        if (t < 256) ((float4*)o)[t] = make_float4(0.f, 0.f, 0.f, 0.f);
        return;
    }

    // Folded weights in registers (independent of compaction; load before barrier)
    const float4* V4 = (const float4*)(ws + OFF_V);
    float4 v0 = V4[0 * 64 + lane];
    float4 v1 = V4[1 * 64 + lane];
    float4 v2 = V4[2 * 64 + lane];
    float4 v3 = V4[3 * 64 + lane];
    float4 cbv = *(const float4*)(ws + OFF_CB);
    float cb = (lane & 1) ? ((lane & 2) ? cbv.w : cbv.y)
                          : ((lane & 2) ? cbv.z : cbv.x);   // head = lane&3

    // Compact bucket id slices into LDS (2 strided iters)
    for (int tt = t; tt < NCOPY * CAP; tt += 512) {
        int cp = tt >> 6, j = tt & (CAP - 1);
        if ((unsigned)j < cc[cp])
            rowbuf[pre[cp] + j] = bucket[(cp * NCLS + c) * CAP + j];
    }
    __syncthreads();

    const float4* ch4 = (const float4*)ch;
    const uint4*  rb4 = (const uint4*)rowbuf;
    const float4 z = make_float4(0.f, 0.f, 0.f, 0.f);

    float4 a0 = z, a1 = z, a2 = z, a3 = z, dsum = z;

    // Wave w owns rows {8w..8w+7} + 64k. Lane owns channels 4*lane..4*lane+3.
    {
        unsigned r = 8u * (unsigned)wave;
        float4 xA0 = z, xA1 = z, xA2 = z, xA3 = z,
               xA4 = z, xA5 = z, xA6 = z, xA7 = z;
        if (r < cnt) {                    // preload iteration 0's 8 rows
            uint4 iL = rb4[r >> 2], iH = rb4[(r >> 2) + 1];
            /*r+0 valid*/     xA0 = ch4[(size_t)iL.x * 64 + lane];
            if (r + 1 < cnt)  xA1 = ch4[(size_t)iL.y * 64 + lane];
            if (r + 2 < cnt)  xA2 = ch4[(size_t)iL.z * 64 + lane];
            if (r + 3 < cnt)  xA3 = ch4[(size_t)iL.w * 64 + lane];
            if (r + 4 < cnt)  xA4 = ch4[(size_t)iH.x * 64 + lane];
            if (r + 5 < cnt)  xA5 = ch4[(size_t)iH.y * 64 + lane];
            if (r + 6 < cnt)  xA6 = ch4[(size_t)iH.z * 64 + lane];
            if (r + 7 < cnt)  xA7 = ch4[(size_t)iH.w * 64 + lane];
        }
        for (; r < cnt; r += 64) {
            // ---- prefetch next iteration's 8 rows (r+64) ----
            unsigned rn = r + 64;
            float4 xB0 = z, xB1 = z, xB2 = z, xB3 = z,
                   xB4 = z, xB5 = z, xB6 = z, xB7 = z;
            if (rn < cnt) {
                uint4 jL = rb4[rn >> 2], jH = rb4[(rn >> 2) + 1];
                /*rn valid*/       xB0 = ch4[(size_t)jL.x * 64 + lane];
                if (rn + 1 < cnt)  xB1 = ch4[(size_t)jL.y * 64 + lane];
                if (rn + 2 < cnt)  xB2 = ch4[(size_t)jL.z * 64 + lane];
                if (rn + 3 < cnt)  xB3 = ch4[(size_t)jL.w * 64 + lane];
                if (rn + 4 < cnt)  xB4 = ch4[(size_t)jH.x * 64 + lane];
                if (rn + 5 < cnt)  xB5 = ch4[(size_t)jH.y * 64 + lane];
                if (rn + 6 < cnt)  xB6 = ch4[(size_t)jH.z * 64 + lane];
                if (rn + 7 < cnt)  xB7 = ch4[(size_t)jH.w * 64 + lane];
            }

            // ---- phase 1: per-row dot + quad-transpose partial ----
            // After this, E_ on lane l = head (l&3) partial summed over l's quad.
            float e0, e1, e2, e3, e4, e5, e6, e7;
#define QSCORE(X_, E_) do {                                                    \
            float p0 = X_.x * v0.x + X_.y * v0.y + X_.z * v0.z + X_.w * v0.w;  \
            float p1 = X_.x * v1.x + X_.y * v1.y + X_.z * v1.z + X_.w * v1.w;  \
            float p2 = X_.x * v2.x + X_.y * v2.y + X_.z * v2.z + X_.w * v2.w;  \
            float p3 = X_.x * v3.x + X_.y * v3.y + X_.z * v3.z + X_.w * v3.w;  \
            float a01 = (lane & 1) ? p1 : p0;                                  \
            float b01 = (lane & 1) ? p0 : p1;                                  \
            b01 = __shfl_xor(b01, 1);  a01 += b01;                             \
            float a23 = (lane & 1) ? p3 : p2;                                  \
            float b23 = (lane & 1) ? p2 : p3;                                  \
            b23 = __shfl_xor(b23, 1);  a23 += b23;                             \
            E_ = (lane & 2) ? a23 : a01;                                       \
            float f2 = (lane & 2) ? a01 : a23;                                 \
            f2 = __shfl_xor(f2, 2);    E_ += f2;                               \
        } while (0)
            QSCORE(xA0, e0); QSCORE(xA1, e1); QSCORE(xA2, e2); QSCORE(xA3, e3);
            QSCORE(xA4, e4); QSCORE(xA5, e5); QSCORE(xA6, e6); QSCORE(xA7, e7);
#undef QSCORE

            // ---- phase 2: 4-level butterfly, level-by-level across 8 rows ----
            // (8 independent chains interleaved -> DS latency pipelined, not serial)
            e0 += __shfl_xor(e0, 4);  e1 += __shfl_xor(e1, 4);
            e2 += __shfl_xor(e2, 4);  e3 += __shfl_xor(e3, 4);
            e4 += __shfl_xor(e4, 4);  e5 += __shfl_xor(e5, 4);
            e6 += __shfl_xor(e6, 4);  e7 += __shfl_xor(e7, 4);
            e0 += __shfl_xor(e0, 8);  e1 += __shfl_xor(e1, 8);
            e2 += __shfl_xor(e2, 8);  e3 += __shfl_xor(e3, 8);
            e4 += __shfl_xor(e4, 8);  e5 += __shfl_xor(e5, 8);
            e6 += __shfl_xor(e6, 8);  e7 += __shfl_xor(e7, 8);
            e0 += __shfl_xor(e0, 16); e1 += __shfl_xor(e1, 16);
            e2 += __shfl_xor(e2, 16); e3 += __shfl_xor(e3, 16);
            e4 += __shfl_xor(e4, 16); e5 += __shfl_xor(e5, 16);
            e6 += __shfl_xor(e6, 16); e7 += __shfl_xor(e7, 16);
            e0 += __shfl_xor(e0, 32); e1 += __shfl_xor(e1, 32);
            e2 += __shfl_xor(e2, 32); e3 += __shfl_xor(e3, 32);
            e4 += __shfl_xor(e4, 32); e5 += __shfl_xor(e5, 32);
            e6 += __shfl_xor(e6, 32); e7 += __shfl_xor(e7, 32);

            // ---- phase 3: leaky-relu + exp + validity gate (8-wide ILP) ----
            float pe0, pe1, pe2, pe3, pe4, pe5, pe6, pe7;
#define PEXP(E_, J_, P_) do {                                                  \
            float s = E_ + cb;                                                 \
            s = s >= 0.0f ? s : 0.2f * s;                                      \
            P_ = __expf(s) * ((r + (unsigned)(J_) < cnt) ? 1.f : 0.f);         \
        } while (0)
            PEXP(e0, 0, pe0); PEXP(e1, 1, pe1); PEXP(e2, 2, pe2); PEXP(e3, 3, pe3);
            PEXP(e4, 4, pe4); PEXP(e5, 5, pe5); PEXP(e6, 6, pe6); PEXP(e7, 7, pe7);
#undef PEXP

            // ---- phase 4: broadcast heads + accumulate (pure FMA) ----
#define ACC(X_, P_) do {                                                       \
            float h0 = __shfl(P_, 0), h1 = __shfl(P_, 1);                      \
            float h2 = __shfl(P_, 2), h3 = __shfl(P_, 3);                      \
            dsum.x += h0; dsum.y += h1; dsum.z += h2; dsum.w += h3;            \
            a0.x = fmaf(X_.x, h0, a0.x); a0.y = fmaf(X_.y, h0, a0.y);          \
            a0.z = fmaf(X_.z, h0, a0.z); a0.w = fmaf(X_.w, h0, a0.w);          \
            a1.x = fmaf(X_.x, h1, a1.x); a1.y = fmaf(X_.y, h1, a1.y);          \
            a1.z = fmaf(X_.z, h1, a1.z); a1.w = fmaf(X_.w, h1, a1.w);          \
            a2.x = fmaf(X_.x, h2, a2.x); a2.y = fmaf(X_.y, h2, a2.y);          \
            a2.z = fmaf(X_.z, h2, a2.z); a2.w = fmaf(X_.w, h2, a2.w);          \
            a3.x = fmaf(X_.x, h3, a3.x); a3.y = fmaf(X_.y, h3, a3.y);          \
            a3.z = fmaf(X_.z, h3, a3.z); a3.w = fmaf(X_.w, h3, a3.w);          \
        } while (0)
            ACC(xA0, pe0); ACC(xA1, pe1); ACC(xA2, pe2); ACC(xA3, pe3);
            ACC(xA4, pe4); ACC(xA5, pe5); ACC(xA6, pe6); ACC(xA7, pe7);
#undef ACC

            // rotate double buffer
            xA0 = xB0; xA1 = xB1; xA2 = xB2; xA3 = xB3;
            xA4 = xB4; xA5 = xB5; xA6 = xB6; xA7 = xB7;
        }
    }

    // Paired-wave pre-reduction: waves 0-3 store, waves 4-7 add in place
    if (wave < 4) {
        sAcc[0][wave][lane] = a0; sAcc[1][wave][lane] = a1;
        sAcc[2][wave][lane] = a2; sAcc[3][wave][lane] = a3;
    }
    if (lane == 0) sDs[wave] = dsum;   // dsum is lane-uniform: store, do NOT reduce
    __syncthreads();
    if (wave >= 4) {
        int w = wave - 4;
        float4 q;
        q = sAcc[0][w][lane]; q.x += a0.x; q.y += a0.y; q.z += a0.z; q.w += a0.w; sAcc[0][w][lane] = q;
        q = sAcc[1][w][lane]; q.x += a1.x; q.y += a1.y; q.z += a1.z; q.w += a1.w; sAcc[1][w][lane] = q;
        q = sAcc[2][w][lane]; q.x += a2.x; q.y += a2.y; q.z += a2.z; q.w += a2.w; sAcc[2][w][lane] = q;
        q = sAcc[3][w][lane]; q.x += a3.x; q.y += a3.y; q.z += a3.z; q.w += a3.w; sAcc[3][w][lane] = q;
    }
    __syncthreads();

    // Epilogue: wave h (h<4) reduces head h across the 4 merged partials + 8 denoms
    if (wave < NHEAD) {
        float4 q0 = sAcc[wave][0][lane], q1 = sAcc[wave][1][lane],
               q2 = sAcc[wave][2][lane], q3 = sAcc[wave][3][lane];
        float4 acc = make_float4((q0.x + q1.x) + (q2.x + q3.x),
                                 (q0.y + q1.y) + (q2.y + q3.y),
                                 (q0.z + q1.z) + (q2.z + q3.z),
                                 (q0.w + q1.w) + (q2.w + q3.w));
        float4 d0 = sDs[0], d1 = sDs[1], d2 = sDs[2], d3 = sDs[3];
        float4 d4 = sDs[4], d5 = sDs[5], d6 = sDs[6], d7 = sDs[7];
        float4 dt = make_float4(((d0.x + d1.x) + (d2.x + d3.x)) + ((d4.x + d5.x) + (d6.x + d7.x)),
                                ((d0.y + d1.y) + (d2.y + d3.y)) + ((d4.y + d5.y) + (d6.y + d7.y)),
                                ((d0.z + d1.z) + (d2.z + d3.z)) + ((d4.z + d5.z) + (d6.z + d7.z)),
                                ((d0.w + d1.w) + (d2.w + d3.w)) + ((d4.w + d5.w) + (d6.w + d7.w)));
        float dh = (wave == 0) ? dt.x : (wave == 1) ? dt.y : (wave == 2) ? dt.z : dt.w;
        float inv = 1.0f / dh;
        ((float4*)o)[wave * 64 + lane] =
            make_float4(acc.x * inv, acc.y * inv, acc.z * inv, acc.w * inv);
    }
}

extern "C" void kernel_launch(void* const* d_in, const int* in_sizes, int n_in,
                              void* d_out, int out_size, void* d_ws, size_t ws_size,
                              hipStream_t stream) {
    const float* ch    = (const float*)d_in[0];
    const float* W_lin = (const float*)d_in[1];
    const float* b_lin = (const float*)d_in[2];
    const float* W_att = (const float*)d_in[3];
    const float* b_att = (const float*)d_in[4];
    const int*   y     = (const int*)d_in[5];
    float* out = (float*)d_out;
    float* ws  = (float*)d_ws;  // ~4.2 MB used

    k_prep  <<<NHEAD + 63, 256, 0, stream>>>(W_lin, b_lin, W_att, b_att, ws);
    k_bucket<<<(N_ROWS / 2 + 255) / 256, 256, 0, stream>>>(y, ws);
    k_pool  <<<NCLS, 512, 0, stream>>>(ch, out, ws);
}

// Round 6
// 190.589 us; speedup vs baseline: 1.0240x; 1.0240x over previous
//
#include <hip/hip_runtime.h>
#include <math.h>

// Problem constants
#define N_ROWS 100000
#define IN_C   256
#define OUT_C  128
#define NHEAD  4
#define NCLS   1000
#define NCOPY  16      // privatization factor for histogram/buckets
#define CAP    64      // bucket capacity per (copy,class); lambda=6.25, ~10-sigma margin

// Workspace layout (float/uint elements); ~1.04M elems = 4.2 MB
#define OFF_V      0          // 1024: folded V[4][256]
#define OFF_CB     1024       // 4:    folded bias c[4]
#define OFF_CNT    1032       // NCOPY*NCLS = 16000 privatized counters
#define OFF_BUCKET 17032      // NCOPY*NCLS*CAP = 1,024,000 row-id buckets

// ---- K1: fused counter zero + weight folding ----
__global__ __launch_bounds__(256) void k_prep(const float* __restrict__ W_lin,
                                              const float* __restrict__ b_lin,
                                              const float* __restrict__ W_att,
                                              const float* __restrict__ b_att,
                                              float* __restrict__ ws) {
    const int b = blockIdx.x, t = threadIdx.x;
    if (b >= NHEAD) {
        int i = (b - NHEAD) * 256 + t;   // 63*256 = 16128 >= 16000
        if (i < NCOPY * NCLS) ((unsigned*)(ws + OFF_CNT))[i] = 0u;
        return;
    }
    __shared__ float sw[OUT_C];
    __shared__ float rb[256];
    if (t < OUT_C) sw[t] = W_att[t];
    __syncthreads();
    const float* wl = W_lin + (size_t)(b * OUT_C) * IN_C + t;
    float s0 = 0.f, s1 = 0.f, s2 = 0.f, s3 = 0.f;
    #pragma unroll 8
    for (int o = 0; o < OUT_C; o += 4) {
        s0 = fmaf(wl[(size_t)(o + 0) * IN_C], sw[o + 0], s0);
        s1 = fmaf(wl[(size_t)(o + 1) * IN_C], sw[o + 1], s1);
        s2 = fmaf(wl[(size_t)(o + 2) * IN_C], sw[o + 2], s2);
        s3 = fmaf(wl[(size_t)(o + 3) * IN_C], sw[o + 3], s3);
    }
    (ws + OFF_V)[b * IN_C + t] = (s0 + s1) + (s2 + s3);
    rb[t] = (t < OUT_C) ? b_lin[b * OUT_C + t] * sw[t] : 0.f;
    __syncthreads();
    for (int d = 128; d; d >>= 1) {
        if (t < d) rb[t] += rb[t + d];
        __syncthreads();
    }
    if (t == 0) (ws + OFF_CB)[b] = rb[0] + b_att[0];
}

// ---- K2: bucket rows by class (reads ONLY y — no ch traffic) ----
__global__ __launch_bounds__(256) void k_bucket(const int* __restrict__ y,
                                                float* __restrict__ ws) {
    int n0 = (blockIdx.x * 256 + threadIdx.x) * 2;
    if (n0 >= N_ROWS) return;
    unsigned* cnt    = (unsigned*)(ws + OFF_CNT);
    unsigned* bucket = (unsigned*)(ws + OFF_BUCKET);
    int2 yv = *(const int2*)(y + n0);          // N_ROWS even; n0+1 always valid
    unsigned cp = (blockIdx.x & (NCOPY - 1)) * NCLS;
    unsigned i0 = cp + (unsigned)yv.x;
    unsigned p0 = atomicAdd(&cnt[i0], 1u);     // ~6.25 adds/address avg
    if (p0 < CAP) bucket[i0 * CAP + p0] = (unsigned)n0;
    unsigned i1 = cp + (unsigned)yv.y;
    unsigned p1 = atomicAdd(&cnt[i1], 1u);
    if (p1 < CAP) bucket[i1 * CAP + p1] = (unsigned)(n0 + 1);
}

// DPP cross-lane add helper: E_ += value pulled via DPP pattern CTRL_ (VALU pipe,
// not DS). CTRL_: 0xB1 = quad_perm xor1, 0x4E = quad_perm xor2,
// 0x124 = row_ror:4, 0x128 = row_ror:8 (rotation preserves lane%4 head classes).
#define DPP_ADD(E_, CTRL_)                                                     \
    E_ += __int_as_float(__builtin_amdgcn_update_dpp(                          \
            0, __float_as_int(E_), (CTRL_), 0xF, 0xF, true))

// ---- K3: single-pass pooling ----
// v3: DS-pipe de-saturation. Rounds 2+4 both sat at ~60us with VALUBusy 24-26%
// and FETCH/ILP changes neutral -> the single per-CU DS pipe (shared by 4
// SIMDs) is the suspect: 11 shuffle DS-ops vs ~45 VALU ops per row gives
// DS ~3x oversubscribed and predicts exactly VALUBusy~25%. This version keeps
// the identical dataflow but moves 9/11 cross-lane ops to the VALU pipe:
// quad transpose -> DPP quad_perm; xor4/xor8 -> DPP row_ror:4/8; head
// broadcasts -> v_readlane (constant lanes 0-3, results in SGPRs).
// Only xor16/xor32 remain as DS shuffles (2 per row).
__global__ __launch_bounds__(512) void k_pool(const float* __restrict__ ch,
                                              float* __restrict__ out,
                                              const float* __restrict__ ws) {
    __shared__ unsigned rowbuf[NCOPY * CAP + 8];  // +8 pad: uint4 reads stay in-bounds
    __shared__ float4   sAcc[NHEAD][4][64];       // paired-wave partials (16 KB)
    __shared__ float4   sDs[8];                   // per-wave denom partials
    const int c = blockIdx.x, t = threadIdx.x;
    const int wave = t >> 6, lane = t & 63;
    const unsigned* cntA   = (const unsigned*)(ws + OFF_CNT);
    const unsigned* bucket = (const unsigned*)(ws + OFF_BUCKET);
    float* o = out + (size_t)c * (NHEAD * IN_C);

    // Per-copy counts (uniform) + exclusive prefix + total
    unsigned cc[NCOPY], pre[NCOPY];
    unsigned cnt = 0;
    #pragma unroll
    for (int cp = 0; cp < NCOPY; ++cp) {
        unsigned v = cntA[cp * NCLS + c];
        cc[cp] = v > CAP ? CAP : v;
        pre[cp] = cnt;
        cnt += cc[cp];
    }
    if (cnt == 0) {  // empty segment -> zeros
        if (t < 256) ((float4*)o)[t] = make_float4(0.f, 0.f, 0.f, 0.f);
        return;
    }

    // Folded weights in registers (independent of compaction; load before barrier)
    const float4* V4 = (const float4*)(ws + OFF_V);
    float4 v0 = V4[0 * 64 + lane];
    float4 v1 = V4[1 * 64 + lane];
    float4 v2 = V4[2 * 64 + lane];
    float4 v3 = V4[3 * 64 + lane];
    float4 cbv = *(const float4*)(ws + OFF_CB);
    float cb = (lane & 1) ? ((lane & 2) ? cbv.w : cbv.y)
                          : ((lane & 2) ? cbv.z : cbv.x);   // head = lane&3

    // Compact bucket id slices into LDS (2 strided iters)
    for (int tt = t; tt < NCOPY * CAP; tt += 512) {
        int cp = tt >> 6, j = tt & (CAP - 1);
        if ((unsigned)j < cc[cp])
            rowbuf[pre[cp] + j] = bucket[(cp * NCLS + c) * CAP + j];
    }
    __syncthreads();

    const float4* ch4 = (const float4*)ch;
    const uint4*  rb4 = (const uint4*)rowbuf;
    const float4 z = make_float4(0.f, 0.f, 0.f, 0.f);

    float4 a0 = z, a1 = z, a2 = z, a3 = z, dsum = z;

    // Wave w owns rows {8w..8w+7} + 64k. Lane owns channels 4*lane..4*lane+3.
    {
        unsigned r = 8u * (unsigned)wave;
        float4 xA0 = z, xA1 = z, xA2 = z, xA3 = z,
               xA4 = z, xA5 = z, xA6 = z, xA7 = z;
        if (r < cnt) {                    // preload iteration 0's 8 rows
            uint4 iL = rb4[r >> 2], iH = rb4[(r >> 2) + 1];
            /*r+0 valid*/     xA0 = ch4[(size_t)iL.x * 64 + lane];
            if (r + 1 < cnt)  xA1 = ch4[(size_t)iL.y * 64 + lane];
            if (r + 2 < cnt)  xA2 = ch4[(size_t)iL.z * 64 + lane];
            if (r + 3 < cnt)  xA3 = ch4[(size_t)iL.w * 64 + lane];
            if (r + 4 < cnt)  xA4 = ch4[(size_t)iH.x * 64 + lane];
            if (r + 5 < cnt)  xA5 = ch4[(size_t)iH.y * 64 + lane];
            if (r + 6 < cnt)  xA6 = ch4[(size_t)iH.z * 64 + lane];
            if (r + 7 < cnt)  xA7 = ch4[(size_t)iH.w * 64 + lane];
        }
        for (; r < cnt; r += 64) {
            // ---- prefetch next iteration's 8 rows (r+64) ----
            unsigned rn = r + 64;
            float4 xB0 = z, xB1 = z, xB2 = z, xB3 = z,
                   xB4 = z, xB5 = z, xB6 = z, xB7 = z;
            if (rn < cnt) {
                uint4 jL = rb4[rn >> 2], jH = rb4[(rn >> 2) + 1];
                /*rn valid*/       xB0 = ch4[(size_t)jL.x * 64 + lane];
                if (rn + 1 < cnt)  xB1 = ch4[(size_t)jL.y * 64 + lane];
                if (rn + 2 < cnt)  xB2 = ch4[(size_t)jL.z * 64 + lane];
                if (rn + 3 < cnt)  xB3 = ch4[(size_t)jL.w * 64 + lane];
                if (rn + 4 < cnt)  xB4 = ch4[(size_t)jH.x * 64 + lane];
                if (rn + 5 < cnt)  xB5 = ch4[(size_t)jH.y * 64 + lane];
                if (rn + 6 < cnt)  xB6 = ch4[(size_t)jH.z * 64 + lane];
                if (rn + 7 < cnt)  xB7 = ch4[(size_t)jH.w * 64 + lane];
            }

            // ---- phase 1: per-row dot + quad transpose (DPP, VALU pipe) ----
            // After this, E_ on lane l = head (l&3) partial summed over l's quad.
            float e0, e1, e2, e3, e4, e5, e6, e7;
#define QSCORE(X_, E_) do {                                                    \
            float p0 = X_.x * v0.x + X_.y * v0.y + X_.z * v0.z + X_.w * v0.w;  \
            float p1 = X_.x * v1.x + X_.y * v1.y + X_.z * v1.z + X_.w * v1.w;  \
            float p2 = X_.x * v2.x + X_.y * v2.y + X_.z * v2.z + X_.w * v2.w;  \
            float p3 = X_.x * v3.x + X_.y * v3.y + X_.z * v3.z + X_.w * v3.w;  \
            float a01 = (lane & 1) ? p1 : p0;                                  \
            float b01 = (lane & 1) ? p0 : p1;                                  \
            a01 += __int_as_float(__builtin_amdgcn_update_dpp(                 \
                     0, __float_as_int(b01), 0xB1, 0xF, 0xF, true));           \
            float a23 = (lane & 1) ? p3 : p2;                                  \
            float b23 = (lane & 1) ? p2 : p3;                                  \
            a23 += __int_as_float(__builtin_amdgcn_update_dpp(                 \
                     0, __float_as_int(b23), 0xB1, 0xF, 0xF, true));           \
            E_ = (lane & 2) ? a23 : a01;                                       \
            float f2 = (lane & 2) ? a01 : a23;                                 \
            E_ += __int_as_float(__builtin_amdgcn_update_dpp(                  \
                     0, __float_as_int(f2), 0x4E, 0xF, 0xF, true));            \
        } while (0)
            QSCORE(xA0, e0); QSCORE(xA1, e1); QSCORE(xA2, e2); QSCORE(xA3, e3);
            QSCORE(xA4, e4); QSCORE(xA5, e5); QSCORE(xA6, e6); QSCORE(xA7, e7);
#undef QSCORE

            // ---- phase 2a: within-16-row reduce via DPP row_ror (VALU pipe) ----
            // ror4 + ror8 sum the 4 quads of each lane%4 class within each row.
            DPP_ADD(e0, 0x124); DPP_ADD(e1, 0x124); DPP_ADD(e2, 0x124); DPP_ADD(e3, 0x124);
            DPP_ADD(e4, 0x124); DPP_ADD(e5, 0x124); DPP_ADD(e6, 0x124); DPP_ADD(e7, 0x124);
            DPP_ADD(e0, 0x128); DPP_ADD(e1, 0x128); DPP_ADD(e2, 0x128); DPP_ADD(e3, 0x128);
            DPP_ADD(e4, 0x128); DPP_ADD(e5, 0x128); DPP_ADD(e6, 0x128); DPP_ADD(e7, 0x128);

            // ---- phase 2b: cross-row levels (the only 2 DS ops per row) ----
            e0 += __shfl_xor(e0, 16); e1 += __shfl_xor(e1, 16);
            e2 += __shfl_xor(e2, 16); e3 += __shfl_xor(e3, 16);
            e4 += __shfl_xor(e4, 16); e5 += __shfl_xor(e5, 16);
            e6 += __shfl_xor(e6, 16); e7 += __shfl_xor(e7, 16);
            e0 += __shfl_xor(e0, 32); e1 += __shfl_xor(e1, 32);
            e2 += __shfl_xor(e2, 32); e3 += __shfl_xor(e3, 32);
            e4 += __shfl_xor(e4, 32); e5 += __shfl_xor(e5, 32);
            e6 += __shfl_xor(e6, 32); e7 += __shfl_xor(e7, 32);

            // ---- phase 3: leaky-relu + exp + validity gate (8-wide ILP) ----
            float pe0, pe1, pe2, pe3, pe4, pe5, pe6, pe7;
#define PEXP(E_, J_, P_) do {                                                  \
            float s = E_ + cb;                                                 \
            s = s >= 0.0f ? s : 0.2f * s;                                      \
            P_ = __expf(s) * ((r + (unsigned)(J_) < cnt) ? 1.f : 0.f);         \
        } while (0)
            PEXP(e0, 0, pe0); PEXP(e1, 1, pe1); PEXP(e2, 2, pe2); PEXP(e3, 3, pe3);
            PEXP(e4, 4, pe4); PEXP(e5, 5, pe5); PEXP(e6, 6, pe6); PEXP(e7, 7, pe7);
#undef PEXP

            // ---- phase 4: head extraction via v_readlane (VALU->SGPR) + FMA ----
            // After the full reduce, lane l holds head (l&3)'s complete exp value,
            // so lanes 0..3 hold heads 0..3. readlane with constant lane index
            // yields wave-uniform SGPRs consumed directly by v_fmac.
#define ACC(X_, P_) do {                                                       \
            float h0 = __int_as_float(__builtin_amdgcn_readlane(__float_as_int(P_), 0)); \
            float h1 = __int_as_float(__builtin_amdgcn_readlane(__float_as_int(P_), 1)); \
            float h2 = __int_as_float(__builtin_amdgcn_readlane(__float_as_int(P_), 2)); \
            float h3 = __int_as_float(__builtin_amdgcn_readlane(__float_as_int(P_), 3)); \
            dsum.x += h0; dsum.y += h1; dsum.z += h2; dsum.w += h3;            \
            a0.x = fmaf(X_.x, h0, a0.x); a0.y = fmaf(X_.y, h0, a0.y);          \
            a0.z = fmaf(X_.z, h0, a0.z); a0.w = fmaf(X_.w, h0, a0.w);          \
            a1.x = fmaf(X_.x, h1, a1.x); a1.y = fmaf(X_.y, h1, a1.y);          \
            a1.z = fmaf(X_.z, h1, a1.z); a1.w = fmaf(X_.w, h1, a1.w);          \
            a2.x = fmaf(X_.x, h2, a2.x); a2.y = fmaf(X_.y, h2, a2.y);          \
            a2.z = fmaf(X_.z, h2, a2.z); a2.w = fmaf(X_.w, h2, a2.w);          \
            a3.x = fmaf(X_.x, h3, a3.x); a3.y = fmaf(X_.y, h3, a3.y);          \
            a3.z = fmaf(X_.z, h3, a3.z); a3.w = fmaf(X_.w, h3, a3.w);          \
        } while (0)
            ACC(xA0, pe0); ACC(xA1, pe1); ACC(xA2, pe2); ACC(xA3, pe3);
            ACC(xA4, pe4); ACC(xA5, pe5); ACC(xA6, pe6); ACC(xA7, pe7);
#undef ACC

            // rotate double buffer
            xA0 = xB0; xA1 = xB1; xA2 = xB2; xA3 = xB3;
            xA4 = xB4; xA5 = xB5; xA6 = xB6; xA7 = xB7;
        }
    }

    // Paired-wave pre-reduction: waves 0-3 store, waves 4-7 add in place
    if (wave < 4) {
        sAcc[0][wave][lane] = a0; sAcc[1][wave][lane] = a1;
        sAcc[2][wave][lane] = a2; sAcc[3][wave][lane] = a3;
    }
    if (lane == 0) sDs[wave] = dsum;   // dsum is lane-uniform: store, do NOT reduce
    __syncthreads();
    if (wave >= 4) {
        int w = wave - 4;
        float4 q;
        q = sAcc[0][w][lane]; q.x += a0.x; q.y += a0.y; q.z += a0.z; q.w += a0.w; sAcc[0][w][lane] = q;
        q = sAcc[1][w][lane]; q.x += a1.x; q.y += a1.y; q.z += a1.z; q.w += a1.w; sAcc[1][w][lane] = q;
        q = sAcc[2][w][lane]; q.x += a2.x; q.y += a2.y; q.z += a2.z; q.w += a2.w; sAcc[2][w][lane] = q;
        q = sAcc[3][w][lane]; q.x += a3.x; q.y += a3.y; q.z += a3.z; q.w += a3.w; sAcc[3][w][lane] = q;
    }
    __syncthreads();

    // Epilogue: wave h (h<4) reduces head h across the 4 merged partials + 8 denoms
    if (wave < NHEAD) {
        float4 q0 = sAcc[wave][0][lane], q1 = sAcc[wave][1][lane],
               q2 = sAcc[wave][2][lane], q3 = sAcc[wave][3][lane];
        float4 acc = make_float4((q0.x + q1.x) + (q2.x + q3.x),
                                 (q0.y + q1.y) + (q2.y + q3.y),
                                 (q0.z + q1.z) + (q2.z + q3.z),
                                 (q0.w + q1.w) + (q2.w + q3.w));
        float4 d0 = sDs[0], d1 = sDs[1], d2 = sDs[2], d3 = sDs[3];
        float4 d4 = sDs[4], d5 = sDs[5], d6 = sDs[6], d7 = sDs[7];
        float4 dt = make_float4(((d0.x + d1.x) + (d2.x + d3.x)) + ((d4.x + d5.x) + (d6.x + d7.x)),
                                ((d0.y + d1.y) + (d2.y + d3.y)) + ((d4.y + d5.y) + (d6.y + d7.y)),
                                ((d0.z + d1.z) + (d2.z + d3.z)) + ((d4.z + d5.z) + (d6.z + d7.z)),
                                ((d0.w + d1.w) + (d2.w + d3.w)) + ((d4.w + d5.w) + (d6.w + d7.w)));
        float dh = (wave == 0) ? dt.x : (wave == 1) ? dt.y : (wave == 2) ? dt.z : dt.w;
        float inv = 1.0f / dh;
        ((float4*)o)[wave * 64 + lane] =
            make_float4(acc.x * inv, acc.y * inv, acc.z * inv, acc.w * inv);
    }
}

extern "C" void kernel_launch(void* const* d_in, const int* in_sizes, int n_in,
                              void* d_out, int out_size, void* d_ws, size_t ws_size,
                              hipStream_t stream) {
    const float* ch    = (const float*)d_in[0];
    const float* W_lin = (const float*)d_in[1];
    const float* b_lin = (const float*)d_in[2];
    const float* W_att = (const float*)d_in[3];
    const float* b_att = (const float*)d_in[4];
    const int*   y     = (const int*)d_in[5];
    float* out = (float*)d_out;
    float* ws  = (float*)d_ws;  // ~4.2 MB used

    k_prep  <<<NHEAD + 63, 256, 0, stream>>>(W_lin, b_lin, W_att, b_att, ws);
    k_bucket<<<(N_ROWS / 2 + 255) / 256, 256, 0, stream>>>(y, ws);
    k_pool  <<<NCLS, 512, 0, stream>>>(ch, out, ws);
}

// Round 7
// 188.873 us; speedup vs baseline: 1.0333x; 1.0091x over previous
//
#include <hip/hip_runtime.h>
#include <math.h>

// Problem constants
#define N_ROWS 100000
#define IN_C   256
#define OUT_C  128
#define NHEAD  4
#define NCLS   1000
#define NCOPY  16      // privatization factor for histogram/buckets
#define CAP    64      // bucket capacity per (copy,class); lambda=6.25, ~10-sigma margin

// Workspace layout (float/uint elements); ~1.04M elems = 4.2 MB
#define OFF_V      0          // 1024: folded V[4][256]
#define OFF_CB     1024       // 4:    folded bias c[4]
#define OFF_CNT    1032       // NCOPY*NCLS = 16000 privatized counters
#define OFF_BUCKET 17032      // NCOPY*NCLS*CAP = 1,024,000 row-id buckets

// ---- K1: fused counter zero + weight folding ----
__global__ __launch_bounds__(256) void k_prep(const float* __restrict__ W_lin,
                                              const float* __restrict__ b_lin,
                                              const float* __restrict__ W_att,
                                              const float* __restrict__ b_att,
                                              float* __restrict__ ws) {
    const int b = blockIdx.x, t = threadIdx.x;
    if (b >= NHEAD) {
        int i = (b - NHEAD) * 256 + t;   // 63*256 = 16128 >= 16000
        if (i < NCOPY * NCLS) ((unsigned*)(ws + OFF_CNT))[i] = 0u;
        return;
    }
    __shared__ float sw[OUT_C];
    __shared__ float rb[256];
    if (t < OUT_C) sw[t] = W_att[t];
    __syncthreads();
    const float* wl = W_lin + (size_t)(b * OUT_C) * IN_C + t;
    float s0 = 0.f, s1 = 0.f, s2 = 0.f, s3 = 0.f;
    #pragma unroll 8
    for (int o = 0; o < OUT_C; o += 4) {
        s0 = fmaf(wl[(size_t)(o + 0) * IN_C], sw[o + 0], s0);
        s1 = fmaf(wl[(size_t)(o + 1) * IN_C], sw[o + 1], s1);
        s2 = fmaf(wl[(size_t)(o + 2) * IN_C], sw[o + 2], s2);
        s3 = fmaf(wl[(size_t)(o + 3) * IN_C], sw[o + 3], s3);
    }
    (ws + OFF_V)[b * IN_C + t] = (s0 + s1) + (s2 + s3);
    rb[t] = (t < OUT_C) ? b_lin[b * OUT_C + t] * sw[t] : 0.f;
    __syncthreads();
    for (int d = 128; d; d >>= 1) {
        if (t < d) rb[t] += rb[t + d];
        __syncthreads();
    }
    if (t == 0) (ws + OFF_CB)[b] = rb[0] + b_att[0];
}

// ---- K2: bucket rows by class (reads ONLY y — no ch traffic) ----
__global__ __launch_bounds__(256) void k_bucket(const int* __restrict__ y,
                                                float* __restrict__ ws) {
    int n0 = (blockIdx.x * 256 + threadIdx.x) * 2;
    if (n0 >= N_ROWS) return;
    unsigned* cnt    = (unsigned*)(ws + OFF_CNT);
    unsigned* bucket = (unsigned*)(ws + OFF_BUCKET);
    int2 yv = *(const int2*)(y + n0);          // N_ROWS even; n0+1 always valid
    unsigned cp = (blockIdx.x & (NCOPY - 1)) * NCLS;
    unsigned i0 = cp + (unsigned)yv.x;
    unsigned p0 = atomicAdd(&cnt[i0], 1u);     // ~6.25 adds/address avg
    if (p0 < CAP) bucket[i0 * CAP + p0] = (unsigned)n0;
    unsigned i1 = cp + (unsigned)yv.y;
    unsigned p1 = atomicAdd(&cnt[i1], 1u);
    if (p1 < CAP) bucket[i1 * CAP + p1] = (unsigned)(n0 + 1);
}

// DPP cross-lane add helper: E_ += value pulled via DPP pattern CTRL_ (VALU pipe,
// not DS). CTRL_: 0xB1 = quad_perm xor1, 0x4E = quad_perm xor2,
// 0x124 = row_ror:4, 0x128 = row_ror:8 (rotation preserves lane%4 head classes).
#define DPP_ADD(E_, CTRL_)                                                     \
    E_ += __int_as_float(__builtin_amdgcn_update_dpp(                          \
            0, __float_as_int(E_), (CTRL_), 0xF, 0xF, true))

// ---- K3: single-pass pooling, ONE WAVE PER CLASS ----
// v4: Rounds 2/4/6 showed three different inner loops all pinned at ~60us with
// FETCH constant (51.6MB), per-CU BW ~3.7GB/s (~3KB in flight/CU) and occupancy
// 18-35% -> the 512-thread barrier-coupled block structure (serial prologue
// chain + only ~2 main iterations/wave + 3 syncthreads) is the bottleneck, not
// the loop body. This version: 1000 blocks x 64 threads, each WAVE owns one
// class end-to-end. No __syncthreads anywhere, no cross-wave reduction (each
// lane already holds the full 4-head x 4-channel result), ~13 steady-state
// iterations of 8 rows with the next 8 prefetched. Math phases are verbatim
// from v3 (passed, absmax 9.8e-4).
__global__ __launch_bounds__(64) void k_pool(const float* __restrict__ ch,
                                             float* __restrict__ out,
                                             const float* __restrict__ ws) {
    __shared__ unsigned rowbuf[NCOPY * CAP + 16];  // 4.2 KB; +16 pad keeps uint4 reads in-bounds
    const int c = blockIdx.x;          // one class per block (= per wave)
    const int lane = threadIdx.x;      // 64 lanes
    const unsigned* cntA   = (const unsigned*)(ws + OFF_CNT);
    const unsigned* bucket = (const unsigned*)(ws + OFF_BUCKET);
    float* o = out + (size_t)c * (NHEAD * IN_C);

    // Per-copy counts (wave-uniform) + exclusive prefix + total
    unsigned cc[NCOPY], pre[NCOPY];
    unsigned cnt = 0;
    #pragma unroll
    for (int cp = 0; cp < NCOPY; ++cp) {
        unsigned v = cntA[cp * NCLS + c];
        cc[cp] = v > CAP ? CAP : v;
        pre[cp] = cnt;
        cnt += cc[cp];
    }
    if (cnt == 0) {  // empty segment -> zeros (4 float4 per lane = full 1024 floats)
        float4 zz = make_float4(0.f, 0.f, 0.f, 0.f);
        float4* o4 = (float4*)o;
        o4[0 * 64 + lane] = zz; o4[1 * 64 + lane] = zz;
        o4[2 * 64 + lane] = zz; o4[3 * 64 + lane] = zz;
        return;
    }

    // Folded weights in registers (per lane: 4 channels x 4 heads)
    const float4* V4 = (const float4*)(ws + OFF_V);
    float4 v0 = V4[0 * 64 + lane];
    float4 v1 = V4[1 * 64 + lane];
    float4 v2 = V4[2 * 64 + lane];
    float4 v3 = V4[3 * 64 + lane];
    float4 cbv = *(const float4*)(ws + OFF_CB);
    float cb = (lane & 1) ? ((lane & 2) ? cbv.w : cbv.y)
                          : ((lane & 2) ? cbv.z : cbv.x);   // head = lane&3

    // Compact bucket id slices into this wave's LDS slice.
    // CAP == 64 == wavefront: iteration k handles copy k, lane j handles slot j.
    // No barrier needed: same-wave ds_write -> ds/vector read ordering via lgkmcnt.
    #pragma unroll
    for (int k = 0; k < NCOPY; ++k) {
        if (lane < (int)cc[k])
            rowbuf[pre[k] + lane] = bucket[(k * NCLS + c) * CAP + lane];
    }

    const float4* ch4 = (const float4*)ch;
    const uint4*  rb4 = (const uint4*)rowbuf;
    const float4 z = make_float4(0.f, 0.f, 0.f, 0.f);

    float4 a0 = z, a1 = z, a2 = z, a3 = z, dsum = z;

    // Main loop: 8 rows per iteration, next 8 prefetched (~13 steady iters).
    {
        float4 xA0 = z, xA1 = z, xA2 = z, xA3 = z,
               xA4 = z, xA5 = z, xA6 = z, xA7 = z;
        {   // preload rows 0..7 (cnt >= 1 here)
            uint4 iL = rb4[0], iH = rb4[1];
            /*0 valid*/   xA0 = ch4[(size_t)iL.x * 64 + lane];
            if (1 < cnt)  xA1 = ch4[(size_t)iL.y * 64 + lane];
            if (2 < cnt)  xA2 = ch4[(size_t)iL.z * 64 + lane];
            if (3 < cnt)  xA3 = ch4[(size_t)iL.w * 64 + lane];
            if (4 < cnt)  xA4 = ch4[(size_t)iH.x * 64 + lane];
            if (5 < cnt)  xA5 = ch4[(size_t)iH.y * 64 + lane];
            if (6 < cnt)  xA6 = ch4[(size_t)iH.z * 64 + lane];
            if (7 < cnt)  xA7 = ch4[(size_t)iH.w * 64 + lane];
        }
        for (unsigned r = 0; r < cnt; r += 8) {
            // ---- prefetch next iteration's 8 rows (r+8) ----
            unsigned rn = r + 8;
            float4 xB0 = z, xB1 = z, xB2 = z, xB3 = z,
                   xB4 = z, xB5 = z, xB6 = z, xB7 = z;
            if (rn < cnt) {
                uint4 jL = rb4[rn >> 2], jH = rb4[(rn >> 2) + 1];
                /*rn valid*/       xB0 = ch4[(size_t)jL.x * 64 + lane];
                if (rn + 1 < cnt)  xB1 = ch4[(size_t)jL.y * 64 + lane];
                if (rn + 2 < cnt)  xB2 = ch4[(size_t)jL.z * 64 + lane];
                if (rn + 3 < cnt)  xB3 = ch4[(size_t)jL.w * 64 + lane];
                if (rn + 4 < cnt)  xB4 = ch4[(size_t)jH.x * 64 + lane];
                if (rn + 5 < cnt)  xB5 = ch4[(size_t)jH.y * 64 + lane];
                if (rn + 6 < cnt)  xB6 = ch4[(size_t)jH.z * 64 + lane];
                if (rn + 7 < cnt)  xB7 = ch4[(size_t)jH.w * 64 + lane];
            }

            // ---- phase 1: per-row dot + quad transpose (DPP, VALU pipe) ----
            float e0, e1, e2, e3, e4, e5, e6, e7;
#define QSCORE(X_, E_) do {                                                    \
            float p0 = X_.x * v0.x + X_.y * v0.y + X_.z * v0.z + X_.w * v0.w;  \
            float p1 = X_.x * v1.x + X_.y * v1.y + X_.z * v1.z + X_.w * v1.w;  \
            float p2 = X_.x * v2.x + X_.y * v2.y + X_.z * v2.z + X_.w * v2.w;  \
            float p3 = X_.x * v3.x + X_.y * v3.y + X_.z * v3.z + X_.w * v3.w;  \
            float a01 = (lane & 1) ? p1 : p0;                                  \
            float b01 = (lane & 1) ? p0 : p1;                                  \
            a01 += __int_as_float(__builtin_amdgcn_update_dpp(                 \
                     0, __float_as_int(b01), 0xB1, 0xF, 0xF, true));           \
            float a23 = (lane & 1) ? p3 : p2;                                  \
            float b23 = (lane & 1) ? p2 : p3;                                  \
            a23 += __int_as_float(__builtin_amdgcn_update_dpp(                 \
                     0, __float_as_int(b23), 0xB1, 0xF, 0xF, true));           \
            E_ = (lane & 2) ? a23 : a01;                                       \
            float f2 = (lane & 2) ? a01 : a23;                                 \
            E_ += __int_as_float(__builtin_amdgcn_update_dpp(                  \
                     0, __float_as_int(f2), 0x4E, 0xF, 0xF, true));            \
        } while (0)
            QSCORE(xA0, e0); QSCORE(xA1, e1); QSCORE(xA2, e2); QSCORE(xA3, e3);
            QSCORE(xA4, e4); QSCORE(xA5, e5); QSCORE(xA6, e6); QSCORE(xA7, e7);
#undef QSCORE

            // ---- phase 2a: within-16-row reduce via DPP row_ror (VALU pipe) ----
            DPP_ADD(e0, 0x124); DPP_ADD(e1, 0x124); DPP_ADD(e2, 0x124); DPP_ADD(e3, 0x124);
            DPP_ADD(e4, 0x124); DPP_ADD(e5, 0x124); DPP_ADD(e6, 0x124); DPP_ADD(e7, 0x124);
            DPP_ADD(e0, 0x128); DPP_ADD(e1, 0x128); DPP_ADD(e2, 0x128); DPP_ADD(e3, 0x128);
            DPP_ADD(e4, 0x128); DPP_ADD(e5, 0x128); DPP_ADD(e6, 0x128); DPP_ADD(e7, 0x128);

            // ---- phase 2b: cross-row levels (2 DS ops per row) ----
            e0 += __shfl_xor(e0, 16); e1 += __shfl_xor(e1, 16);
            e2 += __shfl_xor(e2, 16); e3 += __shfl_xor(e3, 16);
            e4 += __shfl_xor(e4, 16); e5 += __shfl_xor(e5, 16);
            e6 += __shfl_xor(e6, 16); e7 += __shfl_xor(e7, 16);
            e0 += __shfl_xor(e0, 32); e1 += __shfl_xor(e1, 32);
            e2 += __shfl_xor(e2, 32); e3 += __shfl_xor(e3, 32);
            e4 += __shfl_xor(e4, 32); e5 += __shfl_xor(e5, 32);
            e6 += __shfl_xor(e6, 32); e7 += __shfl_xor(e7, 32);

            // ---- phase 3: leaky-relu + exp + validity gate (8-wide ILP) ----
            float pe0, pe1, pe2, pe3, pe4, pe5, pe6, pe7;
#define PEXP(E_, J_, P_) do {                                                  \
            float s = E_ + cb;                                                 \
            s = s >= 0.0f ? s : 0.2f * s;                                      \
            P_ = __expf(s) * ((r + (unsigned)(J_) < cnt) ? 1.f : 0.f);         \
        } while (0)
            PEXP(e0, 0, pe0); PEXP(e1, 1, pe1); PEXP(e2, 2, pe2); PEXP(e3, 3, pe3);
            PEXP(e4, 4, pe4); PEXP(e5, 5, pe5); PEXP(e6, 6, pe6); PEXP(e7, 7, pe7);
#undef PEXP

            // ---- phase 4: head extraction via v_readlane (VALU->SGPR) + FMA ----
#define ACC(X_, P_) do {                                                       \
            float h0 = __int_as_float(__builtin_amdgcn_readlane(__float_as_int(P_), 0)); \
            float h1 = __int_as_float(__builtin_amdgcn_readlane(__float_as_int(P_), 1)); \
            float h2 = __int_as_float(__builtin_amdgcn_readlane(__float_as_int(P_), 2)); \
            float h3 = __int_as_float(__builtin_amdgcn_readlane(__float_as_int(P_), 3)); \
            dsum.x += h0; dsum.y += h1; dsum.z += h2; dsum.w += h3;            \
            a0.x = fmaf(X_.x, h0, a0.x); a0.y = fmaf(X_.y, h0, a0.y);          \
            a0.z = fmaf(X_.z, h0, a0.z); a0.w = fmaf(X_.w, h0, a0.w);          \
            a1.x = fmaf(X_.x, h1, a1.x); a1.y = fmaf(X_.y, h1, a1.y);          \
            a1.z = fmaf(X_.z, h1, a1.z); a1.w = fmaf(X_.w, h1, a1.w);          \
            a2.x = fmaf(X_.x, h2, a2.x); a2.y = fmaf(X_.y, h2, a2.y);          \
            a2.z = fmaf(X_.z, h2, a2.z); a2.w = fmaf(X_.w, h2, a2.w);          \
            a3.x = fmaf(X_.x, h3, a3.x); a3.y = fmaf(X_.y, h3, a3.y);          \
            a3.z = fmaf(X_.z, h3, a3.z); a3.w = fmaf(X_.w, h3, a3.w);          \
        } while (0)
            ACC(xA0, pe0); ACC(xA1, pe1); ACC(xA2, pe2); ACC(xA3, pe3);
            ACC(xA4, pe4); ACC(xA5, pe5); ACC(xA6, pe6); ACC(xA7, pe7);
#undef ACC

            // rotate double buffer
            xA0 = xB0; xA1 = xB1; xA2 = xB2; xA3 = xB3;
            xA4 = xB4; xA5 = xB5; xA6 = xB6; xA7 = xB7;
        }
    }

    // Epilogue: every lane holds the full per-head accumulators for its 4
    // channels AND the full per-head denominators (dsum is lane-uniform).
    float i0 = 1.0f / dsum.x, i1 = 1.0f / dsum.y,
          i2 = 1.0f / dsum.z, i3 = 1.0f / dsum.w;
    float4* o4 = (float4*)o;
    o4[0 * 64 + lane] = make_float4(a0.x * i0, a0.y * i0, a0.z * i0, a0.w * i0);
    o4[1 * 64 + lane] = make_float4(a1.x * i1, a1.y * i1, a1.z * i1, a1.w * i1);
    o4[2 * 64 + lane] = make_float4(a2.x * i2, a2.y * i2, a2.z * i2, a2.w * i2);
    o4[3 * 64 + lane] = make_float4(a3.x * i3, a3.y * i3, a3.z * i3, a3.w * i3);
}

extern "C" void kernel_launch(void* const* d_in, const int* in_sizes, int n_in,
                              void* d_out, int out_size, void* d_ws, size_t ws_size,
                              hipStream_t stream) {
    const float* ch    = (const float*)d_in[0];
    const float* W_lin = (const float*)d_in[1];
    const float* b_lin = (const float*)d_in[2];
    const float* W_att = (const float*)d_in[3];
    const float* b_att = (const float*)d_in[4];
    const int*   y     = (const int*)d_in[5];
    float* out = (float*)d_out;
    float* ws  = (float*)d_ws;  // ~4.2 MB used

    k_prep  <<<NHEAD + 63, 256, 0, stream>>>(W_lin, b_lin, W_att, b_att, ws);
    k_bucket<<<(N_ROWS / 2 + 255) / 256, 256, 0, stream>>>(y, ws);
    k_pool  <<<NCLS, 64, 0, stream>>>(ch, out, ws);
}

// Round 8
// 187.775 us; speedup vs baseline: 1.0394x; 1.0059x over previous
//
#include <hip/hip_runtime.h>
#include <math.h>

// Problem constants
#define N_ROWS 100000
#define IN_C   256
#define OUT_C  128
#define NHEAD  4
#define NCLS   1000
#define NCOPY  16      // privatization factor for histogram/buckets
#define CAP    64      // bucket capacity per (copy,class); lambda=6.25, ~10-sigma margin

// Workspace layout (float/uint elements); ~1.04M elems = 4.2 MB
#define OFF_V      0          // 1024: folded V[4][256]
#define OFF_CB     1024       // 4:    folded bias c[4]
#define OFF_CNT    1032       // NCOPY*NCLS = 16000 privatized counters
#define OFF_BUCKET 17032      // NCOPY*NCLS*CAP = 1,024,000 row-id buckets

// ---- K1: fused counter zero + weight folding ----
__global__ __launch_bounds__(256) void k_prep(const float* __restrict__ W_lin,
                                              const float* __restrict__ b_lin,
                                              const float* __restrict__ W_att,
                                              const float* __restrict__ b_att,
                                              float* __restrict__ ws) {
    const int b = blockIdx.x, t = threadIdx.x;
    if (b >= NHEAD) {
        int i = (b - NHEAD) * 256 + t;   // 63*256 = 16128 >= 16000
        if (i < NCOPY * NCLS) ((unsigned*)(ws + OFF_CNT))[i] = 0u;
        return;
    }
    __shared__ float sw[OUT_C];
    __shared__ float rb[256];
    if (t < OUT_C) sw[t] = W_att[t];
    __syncthreads();
    const float* wl = W_lin + (size_t)(b * OUT_C) * IN_C + t;
    float s0 = 0.f, s1 = 0.f, s2 = 0.f, s3 = 0.f;
    #pragma unroll 8
    for (int o = 0; o < OUT_C; o += 4) {
        s0 = fmaf(wl[(size_t)(o + 0) * IN_C], sw[o + 0], s0);
        s1 = fmaf(wl[(size_t)(o + 1) * IN_C], sw[o + 1], s1);
        s2 = fmaf(wl[(size_t)(o + 2) * IN_C], sw[o + 2], s2);
        s3 = fmaf(wl[(size_t)(o + 3) * IN_C], sw[o + 3], s3);
    }
    (ws + OFF_V)[b * IN_C + t] = (s0 + s1) + (s2 + s3);
    rb[t] = (t < OUT_C) ? b_lin[b * OUT_C + t] * sw[t] : 0.f;
    __syncthreads();
    for (int d = 128; d; d >>= 1) {
        if (t < d) rb[t] += rb[t + d];
        __syncthreads();
    }
    if (t == 0) (ws + OFF_CB)[b] = rb[0] + b_att[0];
}

// ---- K2: bucket rows by class (reads ONLY y — no ch traffic) ----
__global__ __launch_bounds__(256) void k_bucket(const int* __restrict__ y,
                                                float* __restrict__ ws) {
    int n0 = (blockIdx.x * 256 + threadIdx.x) * 2;
    if (n0 >= N_ROWS) return;
    unsigned* cnt    = (unsigned*)(ws + OFF_CNT);
    unsigned* bucket = (unsigned*)(ws + OFF_BUCKET);
    int2 yv = *(const int2*)(y + n0);          // N_ROWS even; n0+1 always valid
    unsigned cp = (blockIdx.x & (NCOPY - 1)) * NCLS;
    unsigned i0 = cp + (unsigned)yv.x;
    unsigned p0 = atomicAdd(&cnt[i0], 1u);     // ~6.25 adds/address avg
    if (p0 < CAP) bucket[i0 * CAP + p0] = (unsigned)n0;
    unsigned i1 = cp + (unsigned)yv.y;
    unsigned p1 = atomicAdd(&cnt[i1], 1u);
    if (p1 < CAP) bucket[i1 * CAP + p1] = (unsigned)(n0 + 1);
}

// DPP cross-lane add helper: E_ += value pulled via DPP pattern CTRL_ (VALU pipe,
// not DS). CTRL_: 0xB1 = quad_perm xor1, 0x4E = quad_perm xor2,
// 0x124 = row_ror:4, 0x128 = row_ror:8 (rotation preserves lane%4 head classes).
#define DPP_ADD(E_, CTRL_)                                                     \
    E_ += __int_as_float(__builtin_amdgcn_update_dpp(                          \
            0, __float_as_int(E_), (CTRL_), 0xF, 0xF, true))

// Non-temporal 16B gather load: row data has ZERO reuse (each row read exactly
// once device-wide), so bypass L1 allocation. v5 theory: per-CU delivered BW
// is pinned at ~3.7GB/s across four kernel structures = ~32x128B miss-lines in
// flight at ~1us = L1 MSHR limit; nt lifts the L1 line-tracking from the path.
typedef float __attribute__((ext_vector_type(4))) f32x4;
static __device__ __forceinline__ float4 ntload4(const float4* p) {
    f32x4 v = __builtin_nontemporal_load((const f32x4*)p);
    return make_float4(v.x, v.y, v.z, v.w);
}

// ---- K3: single-pass pooling ----
// v5 = Round-6 kernel (512 thr, DPP quad_perm/row_ror reduce, 2 DS shuffles,
// readlane head-broadcast, 8-row batch, 1-iter prefetch) + NT gather loads.
// Single-variable A/B vs Round-6's measured 60us.
__global__ __launch_bounds__(512) void k_pool(const float* __restrict__ ch,
                                              float* __restrict__ out,
                                              const float* __restrict__ ws) {
    __shared__ unsigned rowbuf[NCOPY * CAP + 8];  // +8 pad: uint4 reads stay in-bounds
    __shared__ float4   sAcc[NHEAD][4][64];       // paired-wave partials (16 KB)
    __shared__ float4   sDs[8];                   // per-wave denom partials
    const int c = blockIdx.x, t = threadIdx.x;
    const int wave = t >> 6, lane = t & 63;
    const unsigned* cntA   = (const unsigned*)(ws + OFF_CNT);
    const unsigned* bucket = (const unsigned*)(ws + OFF_BUCKET);
    float* o = out + (size_t)c * (NHEAD * IN_C);

    // Per-copy counts (uniform) + exclusive prefix + total
    unsigned cc[NCOPY], pre[NCOPY];
    unsigned cnt = 0;
    #pragma unroll
    for (int cp = 0; cp < NCOPY; ++cp) {
        unsigned v = cntA[cp * NCLS + c];
        cc[cp] = v > CAP ? CAP : v;
        pre[cp] = cnt;
        cnt += cc[cp];
    }
    if (cnt == 0) {  // empty segment -> zeros
        if (t < 256) ((float4*)o)[t] = make_float4(0.f, 0.f, 0.f, 0.f);
        return;
    }

    // Folded weights in registers (independent of compaction; load before barrier)
    const float4* V4 = (const float4*)(ws + OFF_V);
    float4 v0 = V4[0 * 64 + lane];
    float4 v1 = V4[1 * 64 + lane];
    float4 v2 = V4[2 * 64 + lane];
    float4 v3 = V4[3 * 64 + lane];
    float4 cbv = *(const float4*)(ws + OFF_CB);
    float cb = (lane & 1) ? ((lane & 2) ? cbv.w : cbv.y)
                          : ((lane & 2) ? cbv.z : cbv.x);   // head = lane&3

    // Compact bucket id slices into LDS (2 strided iters)
    for (int tt = t; tt < NCOPY * CAP; tt += 512) {
        int cp = tt >> 6, j = tt & (CAP - 1);
        if ((unsigned)j < cc[cp])
            rowbuf[pre[cp] + j] = bucket[(cp * NCLS + c) * CAP + j];
    }
    __syncthreads();

    const float4* ch4 = (const float4*)ch;
    const uint4*  rb4 = (const uint4*)rowbuf;
    const float4 z = make_float4(0.f, 0.f, 0.f, 0.f);

    float4 a0 = z, a1 = z, a2 = z, a3 = z, dsum = z;

    // Wave w owns rows {8w..8w+7} + 64k. Lane owns channels 4*lane..4*lane+3.
    {
        unsigned r = 8u * (unsigned)wave;
        float4 xA0 = z, xA1 = z, xA2 = z, xA3 = z,
               xA4 = z, xA5 = z, xA6 = z, xA7 = z;
        if (r < cnt) {                    // preload iteration 0's 8 rows
            uint4 iL = rb4[r >> 2], iH = rb4[(r >> 2) + 1];
            /*r+0 valid*/     xA0 = ntload4(&ch4[(size_t)iL.x * 64 + lane]);
            if (r + 1 < cnt)  xA1 = ntload4(&ch4[(size_t)iL.y * 64 + lane]);
            if (r + 2 < cnt)  xA2 = ntload4(&ch4[(size_t)iL.z * 64 + lane]);
            if (r + 3 < cnt)  xA3 = ntload4(&ch4[(size_t)iL.w * 64 + lane]);
            if (r + 4 < cnt)  xA4 = ntload4(&ch4[(size_t)iH.x * 64 + lane]);
            if (r + 5 < cnt)  xA5 = ntload4(&ch4[(size_t)iH.y * 64 + lane]);
            if (r + 6 < cnt)  xA6 = ntload4(&ch4[(size_t)iH.z * 64 + lane]);
            if (r + 7 < cnt)  xA7 = ntload4(&ch4[(size_t)iH.w * 64 + lane]);
        }
        for (; r < cnt; r += 64) {
            // ---- prefetch next iteration's 8 rows (r+64) ----
            unsigned rn = r + 64;
            float4 xB0 = z, xB1 = z, xB2 = z, xB3 = z,
                   xB4 = z, xB5 = z, xB6 = z, xB7 = z;
            if (rn < cnt) {
                uint4 jL = rb4[rn >> 2], jH = rb4[(rn >> 2) + 1];
                /*rn valid*/       xB0 = ntload4(&ch4[(size_t)jL.x * 64 + lane]);
                if (rn + 1 < cnt)  xB1 = ntload4(&ch4[(size_t)jL.y * 64 + lane]);
                if (rn + 2 < cnt)  xB2 = ntload4(&ch4[(size_t)jL.z * 64 + lane]);
                if (rn + 3 < cnt)  xB3 = ntload4(&ch4[(size_t)jL.w * 64 + lane]);
                if (rn + 4 < cnt)  xB4 = ntload4(&ch4[(size_t)jH.x * 64 + lane]);
                if (rn + 5 < cnt)  xB5 = ntload4(&ch4[(size_t)jH.y * 64 + lane]);
                if (rn + 6 < cnt)  xB6 = ntload4(&ch4[(size_t)jH.z * 64 + lane]);
                if (rn + 7 < cnt)  xB7 = ntload4(&ch4[(size_t)jH.w * 64 + lane]);
            }

            // ---- phase 1: per-row dot + quad transpose (DPP, VALU pipe) ----
            float e0, e1, e2, e3, e4, e5, e6, e7;
#define QSCORE(X_, E_) do {                                                    \
            float p0 = X_.x * v0.x + X_.y * v0.y + X_.z * v0.z + X_.w * v0.w;  \
            float p1 = X_.x * v1.x + X_.y * v1.y + X_.z * v1.z + X_.w * v1.w;  \
            float p2 = X_.x * v2.x + X_.y * v2.y + X_.z * v2.z + X_.w * v2.w;  \
            float p3 = X_.x * v3.x + X_.y * v3.y + X_.z * v3.z + X_.w * v3.w;  \
            float a01 = (lane & 1) ? p1 : p0;                                  \
            float b01 = (lane & 1) ? p0 : p1;                                  \
            a01 += __int_as_float(__builtin_amdgcn_update_dpp(                 \
                     0, __float_as_int(b01), 0xB1, 0xF, 0xF, true));           \
            float a23 = (lane & 1) ? p3 : p2;                                  \
            float b23 = (lane & 1) ? p2 : p3;                                  \
            a23 += __int_as_float(__builtin_amdgcn_update_dpp(                 \
                     0, __float_as_int(b23), 0xB1, 0xF, 0xF, true));           \
            E_ = (lane & 2) ? a23 : a01;                                       \
            float f2 = (lane & 2) ? a01 : a23;                                 \
            E_ += __int_as_float(__builtin_amdgcn_update_dpp(                  \
                     0, __float_as_int(f2), 0x4E, 0xF, 0xF, true));            \
        } while (0)
            QSCORE(xA0, e0); QSCORE(xA1, e1); QSCORE(xA2, e2); QSCORE(xA3, e3);
            QSCORE(xA4, e4); QSCORE(xA5, e5); QSCORE(xA6, e6); QSCORE(xA7, e7);
#undef QSCORE

            // ---- phase 2a: within-16-row reduce via DPP row_ror (VALU pipe) ----
            DPP_ADD(e0, 0x124); DPP_ADD(e1, 0x124); DPP_ADD(e2, 0x124); DPP_ADD(e3, 0x124);
            DPP_ADD(e4, 0x124); DPP_ADD(e5, 0x124); DPP_ADD(e6, 0x124); DPP_ADD(e7, 0x124);
            DPP_ADD(e0, 0x128); DPP_ADD(e1, 0x128); DPP_ADD(e2, 0x128); DPP_ADD(e3, 0x128);
            DPP_ADD(e4, 0x128); DPP_ADD(e5, 0x128); DPP_ADD(e6, 0x128); DPP_ADD(e7, 0x128);

            // ---- phase 2b: cross-row levels (the only 2 DS ops per row) ----
            e0 += __shfl_xor(e0, 16); e1 += __shfl_xor(e1, 16);
            e2 += __shfl_xor(e2, 16); e3 += __shfl_xor(e3, 16);
            e4 += __shfl_xor(e4, 16); e5 += __shfl_xor(e5, 16);
            e6 += __shfl_xor(e6, 16); e7 += __shfl_xor(e7, 16);
            e0 += __shfl_xor(e0, 32); e1 += __shfl_xor(e1, 32);
            e2 += __shfl_xor(e2, 32); e3 += __shfl_xor(e3, 32);
            e4 += __shfl_xor(e4, 32); e5 += __shfl_xor(e5, 32);
            e6 += __shfl_xor(e6, 32); e7 += __shfl_xor(e7, 32);

            // ---- phase 3: leaky-relu + exp + validity gate (8-wide ILP) ----
            float pe0, pe1, pe2, pe3, pe4, pe5, pe6, pe7;
#define PEXP(E_, J_, P_) do {                                                  \
            float s = E_ + cb;                                                 \
            s = s >= 0.0f ? s : 0.2f * s;                                      \
            P_ = __expf(s) * ((r + (unsigned)(J_) < cnt) ? 1.f : 0.f);         \
        } while (0)
            PEXP(e0, 0, pe0); PEXP(e1, 1, pe1); PEXP(e2, 2, pe2); PEXP(e3, 3, pe3);
            PEXP(e4, 4, pe4); PEXP(e5, 5, pe5); PEXP(e6, 6, pe6); PEXP(e7, 7, pe7);
#undef PEXP

            // ---- phase 4: head extraction via v_readlane (VALU->SGPR) + FMA ----
#define ACC(X_, P_) do {                                                       \
            float h0 = __int_as_float(__builtin_amdgcn_readlane(__float_as_int(P_), 0)); \
            float h1 = __int_as_float(__builtin_amdgcn_readlane(__float_as_int(P_), 1)); \
            float h2 = __int_as_float(__builtin_amdgcn_readlane(__float_as_int(P_), 2)); \
            float h3 = __int_as_float(__builtin_amdgcn_readlane(__float_as_int(P_), 3)); \
            dsum.x += h0; dsum.y += h1; dsum.z += h2; dsum.w += h3;            \
            a0.x = fmaf(X_.x, h0, a0.x); a0.y = fmaf(X_.y, h0, a0.y);          \
            a0.z = fmaf(X_.z, h0, a0.z); a0.w = fmaf(X_.w, h0, a0.w);          \
            a1.x = fmaf(X_.x, h1, a1.x); a1.y = fmaf(X_.y, h1, a1.y);          \
            a1.z = fmaf(X_.z, h1, a1.z); a1.w = fmaf(X_.w, h1, a1.w);          \
            a2.x = fmaf(X_.x, h2, a2.x); a2.y = fmaf(X_.y, h2, a2.y);          \
            a2.z = fmaf(X_.z, h2, a2.z); a2.w = fmaf(X_.w, h2, a2.w);          \
            a3.x = fmaf(X_.x, h3, a3.x); a3.y = fmaf(X_.y, h3, a3.y);          \
            a3.z = fmaf(X_.z, h3, a3.z); a3.w = fmaf(X_.w, h3, a3.w);          \
        } while (0)
            ACC(xA0, pe0); ACC(xA1, pe1); ACC(xA2, pe2); ACC(xA3, pe3);
            ACC(xA4, pe4); ACC(xA5, pe5); ACC(xA6, pe6); ACC(xA7, pe7);
#undef ACC

            // rotate double buffer
            xA0 = xB0; xA1 = xB1; xA2 = xB2; xA3 = xB3;
            xA4 = xB4; xA5 = xB5; xA6 = xB6; xA7 = xB7;
        }
    }

    // Paired-wave pre-reduction: waves 0-3 store, waves 4-7 add in place
    if (wave < 4) {
        sAcc[0][wave][lane] = a0; sAcc[1][wave][lane] = a1;
        sAcc[2][wave][lane] = a2; sAcc[3][wave][lane] = a3;
    }
    if (lane == 0) sDs[wave] = dsum;   // dsum is lane-uniform: store, do NOT reduce
    __syncthreads();
    if (wave >= 4) {
        int w = wave - 4;
        float4 q;
        q = sAcc[0][w][lane]; q.x += a0.x; q.y += a0.y; q.z += a0.z; q.w += a0.w; sAcc[0][w][lane] = q;
        q = sAcc[1][w][lane]; q.x += a1.x; q.y += a1.y; q.z += a1.z; q.w += a1.w; sAcc[1][w][lane] = q;
        q = sAcc[2][w][lane]; q.x += a2.x; q.y += a2.y; q.z += a2.z; q.w += a2.w; sAcc[2][w][lane] = q;
        q = sAcc[3][w][lane]; q.x += a3.x; q.y += a3.y; q.z += a3.z; q.w += a3.w; sAcc[3][w][lane] = q;
    }
    __syncthreads();

    // Epilogue: wave h (h<4) reduces head h across the 4 merged partials + 8 denoms
    if (wave < NHEAD) {
        float4 q0 = sAcc[wave][0][lane], q1 = sAcc[wave][1][lane],
               q2 = sAcc[wave][2][lane], q3 = sAcc[wave][3][lane];
        float4 acc = make_float4((q0.x + q1.x) + (q2.x + q3.x),
                                 (q0.y + q1.y) + (q2.y + q3.y),
                                 (q0.z + q1.z) + (q2.z + q3.z),
                                 (q0.w + q1.w) + (q2.w + q3.w));
        float4 d0 = sDs[0], d1 = sDs[1], d2 = sDs[2], d3 = sDs[3];
        float4 d4 = sDs[4], d5 = sDs[5], d6 = sDs[6], d7 = sDs[7];
        float4 dt = make_float4(((d0.x + d1.x) + (d2.x + d3.x)) + ((d4.x + d5.x) + (d6.x + d7.x)),
                                ((d0.y + d1.y) + (d2.y + d3.y)) + ((d4.y + d5.y) + (d6.y + d7.y)),
                                ((d0.z + d1.z) + (d2.z + d3.z)) + ((d4.z + d5.z) + (d6.z + d7.z)),
                                ((d0.w + d1.w) + (d2.w + d3.w)) + ((d4.w + d5.w) + (d6.w + d7.w)));
        float dh = (wave == 0) ? dt.x : (wave == 1) ? dt.y : (wave == 2) ? dt.z : dt.w;
        float inv = 1.0f / dh;
        ((float4*)o)[wave * 64 + lane] =
            make_float4(acc.x * inv, acc.y * inv, acc.z * inv, acc.w * inv);
    }
}

extern "C" void kernel_launch(void* const* d_in, const int* in_sizes, int n_in,
                              void* d_out, int out_size, void* d_ws, size_t ws_size,
                              hipStream_t stream) {
    const float* ch    = (const float*)d_in[0];
    const float* W_lin = (const float*)d_in[1];
    const float* b_lin = (const float*)d_in[2];
    const float* W_att = (const float*)d_in[3];
    const float* b_att = (const float*)d_in[4];
    const int*   y     = (const int*)d_in[5];
    float* out = (float*)d_out;
    float* ws  = (float*)d_ws;  // ~4.2 MB used

    k_prep  <<<NHEAD + 63, 256, 0, stream>>>(W_lin, b_lin, W_att, b_att, ws);
    k_bucket<<<(N_ROWS / 2 + 255) / 256, 256, 0, stream>>>(y, ws);
    k_pool  <<<NCLS, 512, 0, stream>>>(ch, out, ws);
}